// Round 3
// baseline (605.363 us; speedup 1.0000x reference)
//
#include <hip/hip_runtime.h>
#include <hip/hip_fp16.h>

#define B_ 256
#define T_ 200
#define H_ 256
#define G3 768            // 3*H
#define NV 50001          // V+1
#define KP 128            // K/2 half2 pairs
#define NP4 32            // KP/4 uint4 chunks

using half2v = __attribute__((ext_vector_type(2))) _Float16;

union U32H2 { unsigned int u; half2v h; };

__device__ __forceinline__ float fdot2(half2v a, half2v b, float c) {
  return __builtin_amdgcn_fdot2(a, b, c, false);
}
__device__ __forceinline__ float sigmoidf_(float x) {
  return 1.f / (1.f + __expf(-x));
}
__device__ __forceinline__ float tanhf_(float x) {
  float ax = fabsf(x);
  float e = __expf(-2.f * ax);
  float t = (1.f - e) / (1.f + e);
  return copysignf(t, x);
}

// Pre-pack fp32 [256 x 768] -> uint4-friendly fp16 pairs:
// out[( (p>>2)*G3 + col )*4 + (p&3)] = half2(w[2p][col], w[2p+1][col]),
// so thread `col` loads its K-slice as 32 coalesced dwordx4.
__global__ __launch_bounds__(256) void pack_w(
    const float* __restrict__ wih, const float* __restrict__ whh,
    unsigned int* __restrict__ out) {
  int idx = blockIdx.x * 256 + threadIdx.x;  // 0 .. 2*98304-1
  int m = idx / (KP * G3);
  int r = idx - m * (KP * G3);
  int p = r / G3;
  int col = r - p * G3;
  const float* w = m ? whh : wih;
  U32H2 u;
  u.h.x = (_Float16)w[(size_t)(2 * p) * G3 + col];
  u.h.y = (_Float16)w[(size_t)(2 * p + 1) * G3 + col];
  out[(size_t)m * (KP * G3) + ((size_t)(p >> 2) * G3 + col) * 4 + (p & 3)] = u.u;
}

// Load thread's column slice (full K) as 32 dwordx4, pin into registers so the
// compiler cannot rematerialize the loads inside the sequence loop.
__device__ __forceinline__ void load_w_pinned(const unsigned int* __restrict__ wp,
                                              int col, uint4 Wv[NP4]) {
  const uint4* w4 = (const uint4*)wp;
#pragma unroll
  for (int p4 = 0; p4 < NP4; ++p4) Wv[p4] = w4[(size_t)p4 * G3 + col];
#pragma unroll
  for (int p4 = 0; p4 < NP4; ++p4) {
    asm volatile("" : "+v"(Wv[p4].x), "+v"(Wv[p4].y), "+v"(Wv[p4].z), "+v"(Wv[p4].w));
  }
}

__device__ __forceinline__ float dot_full(const uint4 (&Wv)[NP4],
                                          const unsigned int* __restrict__ x) {
  float a0 = 0.f, a1 = 0.f;
  const uint4* xv = (const uint4*)x;
#pragma unroll
  for (int p4 = 0; p4 < NP4; ++p4) {
    uint4 xx = xv[p4];
    U32H2 wa, wb, wc, wd, xa, xb, xc, xd;
    wa.u = Wv[p4].x; wb.u = Wv[p4].y; wc.u = Wv[p4].z; wd.u = Wv[p4].w;
    xa.u = xx.x; xb.u = xx.y; xc.u = xx.z; xd.u = xx.w;
    a0 = fdot2(wa.h, xa.h, a0);
    a1 = fdot2(wb.h, xb.h, a1);
    a0 = fdot2(wc.h, xc.h, a0);
    a1 = fdot2(wd.h, xd.h, a1);
  }
  return a0 + a1;
}

// Two-token dot: reuse each W register for both tokens per LDS read pair.
__device__ __forceinline__ void dot_full2(const uint4 (&Wv)[NP4],
                                          const unsigned int* __restrict__ x0,
                                          const unsigned int* __restrict__ x1,
                                          float& d0, float& d1) {
  float a0 = 0.f, a1 = 0.f, b0 = 0.f, b1 = 0.f;
  const uint4* xv0 = (const uint4*)x0;
  const uint4* xv1 = (const uint4*)x1;
#pragma unroll
  for (int p4 = 0; p4 < NP4; ++p4) {
    uint4 xx = xv0[p4];
    uint4 yy = xv1[p4];
    U32H2 wa, wb, wc, wd, c;
    wa.u = Wv[p4].x; wb.u = Wv[p4].y; wc.u = Wv[p4].z; wd.u = Wv[p4].w;
    c.u = xx.x; a0 = fdot2(wa.h, c.h, a0);
    c.u = xx.y; a1 = fdot2(wb.h, c.h, a1);
    c.u = xx.z; a0 = fdot2(wc.h, c.h, a0);
    c.u = xx.w; a1 = fdot2(wd.h, c.h, a1);
    c.u = yy.x; b0 = fdot2(wa.h, c.h, b0);
    c.u = yy.y; b1 = fdot2(wb.h, c.h, b1);
    c.u = yy.z; b0 = fdot2(wc.h, c.h, b0);
    c.u = yy.w; b1 = fdot2(wd.h, c.h, b1);
  }
  d0 = a0 + a1;
  d1 = b0 + b1;
}

// K1: gates_x[b,t,col] = emb[ids[b,t]] . w_ih[:,col] + b_ih[col], fp16 out.
// wg g, iter m (0..99) handles row b=(g+m)&255, tokens {2m, 2m+1}.
__global__ __launch_bounds__(768)
__attribute__((amdgpu_waves_per_eu(3, 3)))
void gates_kernel(
    const int* __restrict__ ids, const int* __restrict__ lens,
    const float* __restrict__ emb, const unsigned int* __restrict__ wih_p,
    const float* __restrict__ b_ih, __half* __restrict__ gates) {
  __shared__ __align__(16) __half xpk[2][2][256];
  __shared__ int len_s[256];
  const int tid = threadIdx.x;
  const int g = blockIdx.x;
  const int NM = T_ / 2;  // 100 iterations

  uint4 Wv[NP4];
  load_w_pinned(wih_p, tid, Wv);
  const float bi = b_ih[tid];

  if (tid < 256) len_s[tid] = lens[tid];
  __syncthreads();

  // stage iteration 0 (row b=g, tokens 0,1); t=0 always valid (len>=1)
  if (tid < 256) {
    const int b0r = g & 255;
    xpk[0][0][tid] = (__half)emb[(size_t)ids[(size_t)b0r * T_] * H_ + tid];
    if (1 < len_s[b0r])
      xpk[0][1][tid] = (__half)emb[(size_t)ids[(size_t)b0r * T_ + 1] * H_ + tid];
  }
  __syncthreads();

  for (int m = 0; m < NM; ++m) {
    const int b = (g + m) & 255;
    const int cur = m & 1, nxt = cur ^ 1;

    // prefetch next iteration's embeddings into registers
    float xv0 = 0.f, xv1 = 0.f;
    bool vn0 = false, vn1 = false;
    if (tid < 256 && m + 1 < NM) {
      const int bn = (g + m + 1) & 255;
      const int tn = 2 * (m + 1);
      const int ln = len_s[bn];
      vn0 = (tn < ln);
      vn1 = (tn + 1 < ln);
      if (vn0) xv0 = emb[(size_t)ids[(size_t)bn * T_ + tn] * H_ + tid];
      if (vn1) xv1 = emb[(size_t)ids[(size_t)bn * T_ + tn + 1] * H_ + tid];
    }

    const int lv = len_s[b] - 2 * m;  // valid tokens this iter (clamped)
    if (lv >= 2) {
      float d0, d1;
      dot_full2(Wv, (const unsigned int*)&xpk[cur][0][0],
                (const unsigned int*)&xpk[cur][1][0], d0, d1);
      size_t base = ((size_t)b * T_ + 2 * m) * G3 + tid;
      gates[base] = (__half)(d0 + bi);
      gates[base + G3] = (__half)(d1 + bi);
    } else if (lv == 1) {
      float d0 = dot_full(Wv, (const unsigned int*)&xpk[cur][0][0]);
      gates[((size_t)b * T_ + 2 * m) * G3 + tid] = (__half)(d0 + bi);
    }

    if (tid < 256) {
      if (vn0) xpk[nxt][0][tid] = (__half)xv0;
      if (vn1) xpk[nxt][1][tid] = (__half)xv1;
    }
    __syncthreads();
  }
}

// K2: sequential GRU recurrence, one wg per batch row, w_hh register-resident.
__global__ __launch_bounds__(768)
__attribute__((amdgpu_waves_per_eu(3, 3)))
void rec_kernel(
    const int* __restrict__ lens, const unsigned int* __restrict__ whh_p,
    const float* __restrict__ b_hh, const __half* __restrict__ gates,
    float* __restrict__ hfin) {
  __shared__ float rec[G3];
  __shared__ __align__(16) __half hpk[256];
  const int tid = threadIdx.x;
  const int b = blockIdx.x;

  uint4 Wv[NP4];
  load_w_pinned(whh_p, tid, Wv);

  const int len = lens[b];
  float bh0 = 0.f, bh1 = 0.f, bh2 = 0.f;
  float h = 0.f;
  if (tid < 256) {
    bh0 = b_hh[tid];
    bh1 = b_hh[256 + tid];
    bh2 = b_hh[512 + tid];
    hpk[tid] = (__half)0.f;
  }
  __syncthreads();

  const __half* gp = gates + (size_t)b * T_ * G3 + tid;
  for (int t = 0; t < len; ++t) {
    float gxz = 0.f, gxr = 0.f, gxh = 0.f;
    if (tid < 256) {  // prefetch this step's input gates; used after barrier
      const __half* gpt = gp + (size_t)t * G3;
      gxz = (float)gpt[0];
      gxr = (float)gpt[256];
      gxh = (float)gpt[512];
    }
    float d = dot_full(Wv, (const unsigned int*)&hpk[0]);
    rec[tid] = d;
    __syncthreads();
    if (tid < 256) {
      float z = sigmoidf_(gxz + rec[tid] + bh0);
      float r = sigmoidf_(gxr + rec[256 + tid] + bh1);
      float hh = tanhf_(gxh + r * (rec[512 + tid] + bh2));
      h = z * h + (1.f - z) * hh;
      hpk[tid] = (__half)h;
    }
    __syncthreads();
  }
  if (tid < 256) hfin[(size_t)b * H_ + tid] = h;
}

// K3: logits[256 x 50001] = hfin @ emb^T, fp32 tiled GEMM (unchanged).
__global__ __launch_bounds__(256) void logits_kernel(
    const float* __restrict__ hfin, const float* __restrict__ emb,
    float* __restrict__ out) {
  __shared__ float hsT[32][64];
  __shared__ float esT[32][132];
  const int tid = threadIdx.x;
  const int tx = tid & 15, ty = tid >> 4;
  const int n0 = blockIdx.x * 128;
  const int b0 = blockIdx.y * 64;
  float acc[4][8];
#pragma unroll
  for (int i = 0; i < 4; ++i)
#pragma unroll
    for (int q = 0; q < 8; ++q) acc[i][q] = 0.f;

  for (int k0 = 0; k0 < H_; k0 += 32) {
    {
      int i = tid * 8;
      int r = i >> 5;
      int c = i & 31;
      const float* src = hfin + (size_t)(b0 + r) * H_ + k0 + c;
      float4 a0 = *(const float4*)(src);
      float4 a1 = *(const float4*)(src + 4);
      hsT[c + 0][r] = a0.x; hsT[c + 1][r] = a0.y;
      hsT[c + 2][r] = a0.z; hsT[c + 3][r] = a0.w;
      hsT[c + 4][r] = a1.x; hsT[c + 5][r] = a1.y;
      hsT[c + 6][r] = a1.z; hsT[c + 7][r] = a1.w;
    }
    {
      int r = tid >> 1;
      int c = (tid & 1) * 16;
      int n = n0 + r;
      float4 e0 = {0,0,0,0}, e1 = {0,0,0,0}, e2 = {0,0,0,0}, e3 = {0,0,0,0};
      if (n < NV) {
        const float* src = emb + (size_t)n * H_ + k0 + c;
        e0 = *(const float4*)(src);
        e1 = *(const float4*)(src + 4);
        e2 = *(const float4*)(src + 8);
        e3 = *(const float4*)(src + 12);
      }
      esT[c + 0][r] = e0.x;  esT[c + 1][r] = e0.y;
      esT[c + 2][r] = e0.z;  esT[c + 3][r] = e0.w;
      esT[c + 4][r] = e1.x;  esT[c + 5][r] = e1.y;
      esT[c + 6][r] = e1.z;  esT[c + 7][r] = e1.w;
      esT[c + 8][r] = e2.x;  esT[c + 9][r] = e2.y;
      esT[c + 10][r] = e2.z; esT[c + 11][r] = e2.w;
      esT[c + 12][r] = e3.x; esT[c + 13][r] = e3.y;
      esT[c + 14][r] = e3.z; esT[c + 15][r] = e3.w;
    }
    __syncthreads();
#pragma unroll
    for (int kk = 0; kk < 32; ++kk) {
      float4 hv = *(const float4*)&hsT[kk][ty * 4];
      float4 ea = *(const float4*)&esT[kk][tx * 8];
      float4 eb = *(const float4*)&esT[kk][tx * 8 + 4];
#define ROWFMA(i, hc)                                                     \
  acc[i][0] += hc * ea.x; acc[i][1] += hc * ea.y;                         \
  acc[i][2] += hc * ea.z; acc[i][3] += hc * ea.w;                         \
  acc[i][4] += hc * eb.x; acc[i][5] += hc * eb.y;                         \
  acc[i][6] += hc * eb.z; acc[i][7] += hc * eb.w;
      ROWFMA(0, hv.x)
      ROWFMA(1, hv.y)
      ROWFMA(2, hv.z)
      ROWFMA(3, hv.w)
#undef ROWFMA
    }
    __syncthreads();
  }
#pragma unroll
  for (int i = 0; i < 4; ++i) {
    int bb = b0 + ty * 4 + i;
    float* op = out + (size_t)bb * NV + n0 + tx * 8;
#pragma unroll
    for (int q = 0; q < 8; ++q) {
      int n = n0 + tx * 8 + q;
      if (n < NV) op[q] = acc[i][q];
    }
  }
}

extern "C" void kernel_launch(void* const* d_in, const int* in_sizes, int n_in,
                              void* d_out, int out_size, void* d_ws, size_t ws_size,
                              hipStream_t stream) {
  const int* ids = (const int*)d_in[0];
  const int* lens = (const int*)d_in[1];
  const float* emb = (const float*)d_in[2];
  const float* w_ih = (const float*)d_in[3];
  const float* w_hh = (const float*)d_in[4];
  const float* b_ih = (const float*)d_in[5];
  const float* b_hh = (const float*)d_in[6];
  float* out = (float*)d_out;

  char* ws = (char*)d_ws;
  __half* gates = (__half*)ws;                                   // 78.6 MB
  float* hfin = (float*)(ws + (size_t)B_ * T_ * G3 * sizeof(__half));
  unsigned int* wpack = (unsigned int*)(ws + (size_t)B_ * T_ * G3 * sizeof(__half)
                                        + (size_t)B_ * H_ * sizeof(float));
  unsigned int* wih_p = wpack;                                   // 393 KB
  unsigned int* whh_p = wpack + (size_t)KP * G3;                 // 393 KB

  pack_w<<<dim3(2 * KP * G3 / 256), dim3(256), 0, stream>>>(w_ih, w_hh, wpack);
  gates_kernel<<<dim3(B_), dim3(768), 0, stream>>>(ids, lens, emb, wih_p, b_ih, gates);
  rec_kernel<<<dim3(B_), dim3(768), 0, stream>>>(lens, whh_p, b_hh, gates, hfin);
  logits_kernel<<<dim3((NV + 127) / 128, B_ / 64), dim3(256), 0, stream>>>(hfin, emb, out);
}